// Round 7
// baseline (404.539 us; speedup 1.0000x reference)
//
#include <hip/hip_runtime.h>
#include <math.h>

#define NC1 150
#define HW 196          // 14*14
#define NB 1024
#define DD 32
#define NHD 4
#define HDIM 8
#define KG 2352         // ceil(0.08 * 150*14*14)
#define KCH 10
#define CAP 48          // per-location survivor capacity (avg ~15, +7sd safe)
#define CVS 49          // candV row stride (odd -> conflict-free merge reads)
#define CES 36          // staged CE row stride (16B-aligned rows for float4)
#define KVS 20          // kv row stride in floats (80B rows: b128 writes tile 32 banks)
#define QLS 12          // q_lds row stride in floats (48B: 16B-aligned, 8 start-banks)

typedef float v2f __attribute__((ext_vector_type(2)));

// packed-fp32 32-dot: 16 v_pk_fma_f32 + pair-reduce (vs 32 v_fma_f32)
__device__ __forceinline__ float dot32v(const v2f* __restrict__ xr2,
                                        const float* __restrict__ wr, float bias) {
  const float4* w4 = (const float4*)wr;
  v2f s0 = {bias, 0.f};
  v2f s1 = {0.f, 0.f};
#pragma unroll
  for (int e = 0; e < 8; ++e) {
    float4 w = w4[e];
    v2f wlo = {w.x, w.y}, whi = {w.z, w.w};
    s0 = __builtin_elementwise_fma(xr2[2 * e], wlo, s0);
    s1 = __builtin_elementwise_fma(xr2[2 * e + 1], whi, s1);
  }
  v2f s = s0 + s1;
  return s.x + s.y;
}

// union LDS (float slots):
//  conv phase : XT[42][196] @0 (8232) | WT[42][152] @8232 (6384)  -> 14616
//  tail phase : candV @0 (196*49=9604) | candC u8 @9604 (196*48 B = 2352 slots)
//               | cnt u32 @11956 (196) | CEs @12152 (150*36=5400) -> 17552
#define UNI_F 17552
#define XT_OFF 0
#define WT_OFF 8232
#define CV_OFF 0
#define CC_OFF 9604
#define CNT_OFF 11956
#define CE_OFF 12152

// ---------------- K0 (merged): pos2d [196,32] + conv-weight transpose ----------------
__global__ void prep2_kernel(const float* __restrict__ cw, float* __restrict__ wtg,
                             float* __restrict__ pos) {
  int i = blockIdx.x * 256 + threadIdx.x;
  if (i < HW * DD) {
    int s = i >> 5, d = i & 31;
    int h = s / 14, w = s % 14;
    int p = (d < 16) ? h : w;
    int dd = (d < 16) ? d : d - 16;
    int j = dd >> 1;
    float dv = expf(-(logf(10000.0f) / 16.0f) * (float)(2 * j));
    float ang = (float)p * dv;
    pos[i] = (dd & 1) ? cosf(ang) : sinf(ang);
    return;
  }
  int j = i - HW * DD;
  if (j < 84 * 152) {
    int k = j / 152, c = j - k * 152;
    wtg[j] = (k < 81 && c < NC1) ? cw[c * 81 + k] : 0.f;
  }
}

// ---------------- K1 (fused, R10): conv GEMM -> register radix kth ->
//                  survivor compaction -> per-loc merge top10 + embed + PE ----------
__global__ __launch_bounds__(1024, 8) void fused_kernel(const float* __restrict__ x,
                                                        const float* __restrict__ wtg,
                                                        const float* __restrict__ CE,
                                                        const float* __restrict__ pos,
                                                        float* __restrict__ seqo) {
  __shared__ alignas(16) float uni[UNI_F];   // 70208 B
  __shared__ alignas(16) float xs[784];      // 3136 B
  __shared__ unsigned hist[2048];            // 8192 B
  __shared__ unsigned wsum[4];
  __shared__ unsigned s_prefix, s_krem, s_max;   // total ~79.7 KB -> 2 blocks/CU

  int b = blockIdx.x, tid = threadIdx.x;
  int lane = tid & 63, wid = tid >> 6;

  if (tid < 196) ((float4*)xs)[tid] = ((const float4*)(x + (size_t)b * 784))[tid];
  if (tid == 0) { s_prefix = 0u; s_krem = KG; s_max = 0u; }
  __syncthreads();

  int cg = tid / 49;              // ch-group 0..18 (8 ch each, 152 incl 2 pad)
  int g  = tid - cg * 49;         // loc-group 0..48 (4 locs each, 196 exact)
  bool act = (tid < 931);         // 19*49
  float acc[4][8];
#pragma unroll
  for (int i = 0; i < 4; ++i)
#pragma unroll
    for (int j = 0; j < 8; ++j) acc[i][j] = 0.f;

  float* XT = uni + XT_OFF;       // [42][196]
  float* WT = uni + WT_OFF;       // [42][152]

  for (int kb = 0; kb < 84; kb += 42) {
    // build X^T[kk][s]
    for (int i = tid; i < 42 * 196; i += 1024) {
      int kk = i / 196, s = i - kk * 196;
      int k = kb + kk;
      float v = 0.f;
      if (k < 81) {
        int ki = k / 9, kj = k - ki * 9;
        int h = s / 14, w = s - h * 14;
        int r = 2 * h - 4 + ki, c = 2 * w - 4 + kj;
        if (r >= 0 && r < 28 && c >= 0 && c < 28) v = xs[r * 28 + c];
      }
      XT[i] = v;
    }
    // coalesced float4 copy of pre-transposed weights
    for (int i = tid; i < (42 * 152) / 4; i += 1024)
      ((float4*)WT)[i] = ((const float4*)(wtg + kb * 152))[i];
    __syncthreads();
    if (act) {
      const float* xtp = XT + 4 * g;
      const float* wtp = WT + 8 * cg;
#pragma unroll 7
      for (int kk = 0; kk < 42; ++kk) {
        float4 xv = *(const float4*)(xtp + kk * 196);
        float4 w0 = *(const float4*)(wtp + kk * 152);
        float4 w1 = *(const float4*)(wtp + kk * 152 + 4);
        float xa[4] = {xv.x, xv.y, xv.z, xv.w};
        float wa[8] = {w0.x, w0.y, w0.z, w0.w, w1.x, w1.y, w1.z, w1.w};
#pragma unroll
        for (int i = 0; i < 4; ++i)
#pragma unroll
          for (int j = 0; j < 8; ++j) acc[i][j] += xa[i] * wa[j];
      }
    }
    __syncthreads();              // GEMM reads done before next-phase overwrite
  }

  // ---- ReLU in registers (inactive threads already hold zeros) ----
#pragma unroll
  for (int i = 0; i < 4; ++i)
#pragma unroll
    for (int j = 0; j < 8; ++j) acc[i][j] = fmaxf(acc[i][j], 0.f);

  // ---- kth: 3-pass radix select, histograms fed FROM REGISTERS, zero-skip ----
  for (int pass = 0; pass < 3; ++pass) {
    hist[tid] = 0u; hist[tid + 1024] = 0u;
    __syncthreads();
    int shift = (pass == 0) ? 21 : (pass == 1 ? 10 : 0);
    int bits = (pass == 2) ? 10 : 11;
    unsigned mask = (1u << bits) - 1u;
    unsigned pfx = s_prefix;        // snapshot after barrier
    unsigned krem = s_krem;
    int hishift = shift + bits;
    if (pass == 0) {
      unsigned mymax = 0u;
#pragma unroll
      for (int i = 0; i < 4; ++i)
#pragma unroll
        for (int j = 0; j < 8; ++j) {
          unsigned u = __float_as_uint(acc[i][j]);
          mymax = max(mymax, u);
          if (u) atomicAdd(&hist[u >> 21], 1u);
        }
#pragma unroll
      for (int st = 32; st >= 1; st >>= 1)
        mymax = max(mymax, (unsigned)__shfl_xor((int)mymax, st));
      if (lane == 0) atomicMax(&s_max, mymax);
    } else {
#pragma unroll
      for (int i = 0; i < 4; ++i)
#pragma unroll
        for (int j = 0; j < 8; ++j) {
          unsigned u = __float_as_uint(acc[i][j]);
          if (u && (u >> hishift) == pfx) atomicAdd(&hist[(u >> shift) & mask], 1u);
        }
    }
    __syncthreads();
    int segsz = (1 << bits) >> 8;   // 8 or 4
    unsigned segv = 0u, sufv = 0u;
    if (tid < 256) {
      for (int j = 0; j < segsz; ++j) segv += hist[tid * segsz + j];
      sufv = segv;
#pragma unroll
      for (int st = 1; st < 64; st <<= 1) {
        unsigned o = (unsigned)__shfl_down((int)sufv, st);
        if (lane + st < 64) sufv += o;
      }
      if (lane == 0) wsum[wid] = sufv;
    }
    __syncthreads();
    if (tid < 256) {
      unsigned tail = 0u;
      for (int ww = wid + 1; ww < 4; ++ww) tail += wsum[ww];
      sufv += tail;                    // count in segments >= tid
      unsigned above = sufv - segv;
      if (above < krem && sufv >= krem) {   // unique winner
        unsigned cum = above;
        int dsel = tid * segsz;
        for (int d2 = segsz - 1; d2 >= 0; --d2) {
          int dd = tid * segsz + d2;
          if (cum + hist[dd] >= krem) { dsel = dd; break; }
          cum += hist[dd];
        }
        s_prefix = (pfx << bits) | (unsigned)dsel;
        s_krem = krem - cum;
      }
    }
    __syncthreads();
  }

  // ---- survivor compaction: per-location candidate lists in union LDS ----
  float* candV = uni + CV_OFF;
  unsigned char* candC = (unsigned char*)(uni + CC_OFF);
  unsigned* cnt = (unsigned*)(uni + CNT_OFF);
  if (tid < 196) cnt[tid] = 0u;
  __syncthreads();
  float T = __uint_as_float(s_prefix);
  if (act) {
#pragma unroll
    for (int i = 0; i < 4; ++i) {
      int loc = 4 * g + i;
#pragma unroll
      for (int j = 0; j < 8; ++j) {
        float v = acc[i][j];
        if (v >= T && v > 0.f) {      // pad channels (c>=150) are exact zeros
          unsigned slot = atomicAdd(&cnt[loc], 1u);
          if (slot < CAP) {
            candV[loc * CVS + slot] = v;
            candC[loc * CAP + slot] = (unsigned char)(8 * cg + j);
          }
        }
      }
    }
  }
  __syncthreads();

  // ---- merge (tid<196) overlapped with CE staging (tid>=196) ----
  float* CEs = uni + CE_OFF;          // [150][36], float4-aligned rows
  if (tid >= 196) {
    for (int i = tid - 196; i < NC1 * 32; i += 1024 - 196) {
      int c = i >> 5, e = i & 31;
      CEs[c * CES + e] = CE[i];
    }
  }
  float tv[KCH]; int tc[KCH];
  if (tid < 196) {
    int loc = tid;
    unsigned n = cnt[loc]; if (n > CAP) n = CAP;
#pragma unroll
    for (int k = 0; k < KCH; ++k) { tv[k] = 0.f; tc[k] = 0; }
    for (unsigned jj = 0; jj < n; ++jj) {
      float v = candV[loc * CVS + jj];
      int c = candC[loc * CAP + jj];
      // exact reference semantics: order by value desc, tie -> lower channel
      if (v > tv[KCH - 1] || (v == tv[KCH - 1] && c < tc[KCH - 1])) {
        float iv = v; int ic = c;
#pragma unroll
        for (int j = 0; j < KCH; ++j) {
          bool gt = (iv > tv[j]) || (iv == tv[j] && ic < tc[j]);
          float nv = gt ? iv : tv[j]; int nc = gt ? ic : tc[j];
          float ov = gt ? tv[j] : iv; int oc = gt ? tc[j] : ic;
          tv[j] = nv; tc[j] = nc; iv = ov; ic = oc;
        }
      }
    }
  }
  __syncthreads();                    // CEs staged, merge done

  // ---- embed + PE + write seq ----
  if (tid < 196) {
    float gm = __uint_as_float(s_max);
    float gi = (gm == 0.0f) ? 0.0f : 1.0f / gm;
    float acc2[32];
#pragma unroll
    for (int e = 0; e < 32; ++e) acc2[e] = 0.f;
#pragma unroll
    for (int k = 0; k < KCH; ++k) {   // unused slots have tv=0 -> no-op
      float v = tv[k];
      const float4* cr = (const float4*)(CEs + tc[k] * CES);
#pragma unroll
      for (int e4 = 0; e4 < 8; ++e4) {
        float4 cv = cr[e4];
        acc2[e4 * 4 + 0] += v * cv.x;
        acc2[e4 * 4 + 1] += v * cv.y;
        acc2[e4 * 4 + 2] += v * cv.z;
        acc2[e4 * 4 + 3] += v * cv.w;
      }
    }
    float* op = seqo + ((size_t)b * HW + tid) * DD;
    const float* pr = pos + tid * DD;
#pragma unroll
    for (int e4 = 0; e4 < 8; ++e4) {
      float4 pv = ((const float4*)pr)[e4];
      float4 o;
      o.x = acc2[e4 * 4 + 0] * gi + pv.x;
      o.y = acc2[e4 * 4 + 1] * gi + pv.y;
      o.z = acc2[e4 * 4 + 2] * gi + pv.z;
      o.w = acc2[e4 * 4 + 3] * gi + pv.w;
      ((float4*)op)[e4] = o;
    }
  }
}

// ---------------- K4 (R16): MHA, 2 query rows per phase-2 thread ----
// R15 retro: pk math cut VALUBusy 66->57% but dur stayed ~165us -> attn is
// LDS-PIPE-bound: phase-2 issued 12.25 waves x 196 x 4 ds_read_b128 = 9604
// LDS wave-instrs/block (~110-190us over 4 seq blocks at m134's 6-12cyc/instr).
// R16: each phase-2 thread owns 2 q-rows of one head (s0, s0+98) -> one k/v
// broadcast feeds 2 outputs -> LDS instrs halve (~5500; <=2-addr reads free
// per m136). q passes through q_lds (stride 12 floats, 16B-aligned); read once
// into regs. Total VALU unchanged (~25us << LDS). LDS 113KB, same 1 block/CU.
__global__ __launch_bounds__(832, 3) void attn_kernel(const float* __restrict__ seq,
                                                      const float* __restrict__ Wqkv,
                                                      const float* __restrict__ bqkv,
                                                      float* __restrict__ ctxo) {
  __shared__ alignas(16) float kvs[NHD * HW * KVS];  // 62720 B
  __shared__ alignas(16) float qls[NHD * HW * QLS];  // 37632 B
  __shared__ alignas(16) float swq[96 * DD];         // 12288 B
  __shared__ float sbq[96];
  __shared__ unsigned s_kk[NHD];                     // total ~113 KB

  int b = blockIdx.x, tid = threadIdx.x;
  int h = tid / HW;               // 0..3 (tid<784)
  int s = tid - h * HW;
  bool act = (tid < NHD * HW);

  // hoist global seq row load: HBM latency hides under LDS weight staging
  v2f xr2[16];
  if (act) {
    const float4* row4 = (const float4*)(seq + ((size_t)b * HW + s) * DD);
#pragma unroll
    for (int e = 0; e < 8; ++e) {
      float4 f = row4[e];
      v2f lo = {f.x, f.y}, hi = {f.z, f.w};
      xr2[2 * e] = lo; xr2[2 * e + 1] = hi;
    }
  }
  for (int i = tid; i < (96 * DD) / 4; i += 832)
    ((float4*)swq)[i] = ((const float4*)Wqkv)[i];
  if (tid < 96) sbq[tid] = bqkv[tid];
  if (tid < NHD) s_kk[tid] = 0u;
  __syncthreads();

  if (act) {
    float* kvrow = kvs + (h * HW + s) * KVS;
    // ---- k row (8 packed dots), track k.k ----
    {
      float ka[8]; float kk = 0.f;
#pragma unroll
      for (int d = 0; d < 8; ++d) {
        ka[d] = dot32v(xr2, swq + (32 + h * HDIM + d) * DD, sbq[32 + h * HDIM + d]);
        kk += ka[d] * ka[d];
      }
      float4 k0 = {ka[0], ka[1], ka[2], ka[3]}, k1 = {ka[4], ka[5], ka[6], ka[7]};
      ((float4*)kvrow)[0] = k0; ((float4*)kvrow)[1] = k1;
      atomicMax(&s_kk[h], __float_as_uint(kk));
    }
    // ---- v row ----
    {
      float va[8];
#pragma unroll
      for (int d = 0; d < 8; ++d)
        va[d] = dot32v(xr2, swq + (64 + h * HDIM + d) * DD, sbq[64 + h * HDIM + d]);
      float4 v0 = {va[0], va[1], va[2], va[3]}, v1 = {va[4], va[5], va[6], va[7]};
      ((float4*)kvrow)[2] = v0; ((float4*)kvrow)[3] = v1;
    }
    // ---- q row -> q_lds (consumer thread != producer under 2-row tiling) ----
    {
      float qa8[8];
#pragma unroll
      for (int d = 0; d < 8; ++d)
        qa8[d] = dot32v(xr2, swq + (h * HDIM + d) * DD, sbq[h * HDIM + d]);
      float* qrow = qls + (h * HW + s) * QLS;
      float4 q0 = {qa8[0], qa8[1], qa8[2], qa8[3]}, q1 = {qa8[4], qa8[5], qa8[6], qa8[7]};
      ((float4*)qrow)[0] = q0; ((float4*)qrow)[1] = q1;
    }
  }
  __syncthreads();
  if (tid >= 392) return;

  // ---- phase 2: thread owns q-rows (h2, s0) and (h2, s0+98) ----
  int h2 = tid / 98, s0 = tid - h2 * 98;
  v2f qa[4], qb[4];
  {
    const float4* qra = (const float4*)(qls + (h2 * HW + s0) * QLS);
    const float4* qrb = (const float4*)(qls + (h2 * HW + s0 + 98) * QLS);
    float4 a0 = qra[0], a1 = qra[1], b0 = qrb[0], b1 = qrb[1];
    qa[0].x = a0.x; qa[0].y = a0.y; qa[1].x = a0.z; qa[1].y = a0.w;
    qa[2].x = a1.x; qa[2].y = a1.y; qa[3].x = a1.z; qa[3].y = a1.w;
    qb[0].x = b0.x; qb[0].y = b0.y; qb[1].x = b0.z; qb[1].y = b0.w;
    qb[2].x = b1.x; qb[2].y = b1.y; qb[3].x = b1.z; qb[3].y = b1.w;
  }
  const float scaleL = 0.3535533905932738f * 1.4426950408889634f;  // scale*log2e
  float kkmax = __uint_as_float(s_kk[h2]);
  v2f t2;
  t2 = qa[0] * qa[0];
  t2 = __builtin_elementwise_fma(qa[1], qa[1], t2);
  t2 = __builtin_elementwise_fma(qa[2], qa[2], t2);
  t2 = __builtin_elementwise_fma(qa[3], qa[3], t2);
  float negMLa = -sqrtf((t2.x + t2.y) * kkmax) * scaleL;
  t2 = qb[0] * qb[0];
  t2 = __builtin_elementwise_fma(qb[1], qb[1], t2);
  t2 = __builtin_elementwise_fma(qb[2], qb[2], t2);
  t2 = __builtin_elementwise_fma(qb[3], qb[3], t2);
  float negMLb = -sqrtf((t2.x + t2.y) * kkmax) * scaleL;

  float la = 0.f, lb = 0.f;
  v2f ca01 = {0.f, 0.f}, ca23 = {0.f, 0.f}, ca45 = {0.f, 0.f}, ca67 = {0.f, 0.f};
  v2f cb01 = {0.f, 0.f}, cb23 = {0.f, 0.f}, cb45 = {0.f, 0.f}, cb67 = {0.f, 0.f};
  const float4* kp = (const float4*)(kvs + (h2 * HW) * KVS);
#pragma unroll 2
  for (int t = 0; t < HW; ++t) {
    float4 k0 = kp[0], k1 = kp[1], v0 = kp[2], v1 = kp[3];
    kp += 5;                       // 80B row
    v2f k0lo = {k0.x, k0.y}, k0hi = {k0.z, k0.w};
    v2f k1lo = {k1.x, k1.y}, k1hi = {k1.z, k1.w};
    v2f da = qa[0] * k0lo;
    da = __builtin_elementwise_fma(qa[1], k0hi, da);
    da = __builtin_elementwise_fma(qa[2], k1lo, da);
    da = __builtin_elementwise_fma(qa[3], k1hi, da);
    v2f db = qb[0] * k0lo;
    db = __builtin_elementwise_fma(qb[1], k0hi, db);
    db = __builtin_elementwise_fma(qb[2], k1lo, db);
    db = __builtin_elementwise_fma(qb[3], k1hi, db);
    float pa = exp2f(fmaf(da.x + da.y, scaleL, negMLa));
    float pb = exp2f(fmaf(db.x + db.y, scaleL, negMLb));
    la += pa; lb += pb;
    v2f ppa = {pa, pa}, ppb = {pb, pb};
    v2f v0lo = {v0.x, v0.y}, v0hi = {v0.z, v0.w};
    v2f v1lo = {v1.x, v1.y}, v1hi = {v1.z, v1.w};
    ca01 = __builtin_elementwise_fma(ppa, v0lo, ca01);
    ca23 = __builtin_elementwise_fma(ppa, v0hi, ca23);
    ca45 = __builtin_elementwise_fma(ppa, v1lo, ca45);
    ca67 = __builtin_elementwise_fma(ppa, v1hi, ca67);
    cb01 = __builtin_elementwise_fma(ppb, v0lo, cb01);
    cb23 = __builtin_elementwise_fma(ppb, v0hi, cb23);
    cb45 = __builtin_elementwise_fma(ppb, v1lo, cb45);
    cb67 = __builtin_elementwise_fma(ppb, v1hi, cb67);
  }
  float inva = 1.0f / la, invb = 1.0f / lb;
  float* opa = ctxo + ((size_t)b * HW + s0) * DD + h2 * HDIM;
  float* opb = ctxo + ((size_t)b * HW + s0 + 98) * DD + h2 * HDIM;
  float4 o0, o1;
  o0.x = ca01.x * inva; o0.y = ca01.y * inva; o0.z = ca23.x * inva; o0.w = ca23.y * inva;
  o1.x = ca45.x * inva; o1.y = ca45.y * inva; o1.z = ca67.x * inva; o1.w = ca67.y * inva;
  ((float4*)opa)[0] = o0; ((float4*)opa)[1] = o1;
  o0.x = cb01.x * invb; o0.y = cb01.y * invb; o0.z = cb23.x * invb; o0.w = cb23.y * invb;
  o1.x = cb45.x * invb; o1.y = cb45.y * invb; o1.z = cb67.x * invb; o1.w = cb67.y * invb;
  ((float4*)opb)[0] = o0; ((float4*)opb)[1] = o1;
}

// ---------------- K5: out projection, 1 thread per row (packed fp32) ----------------
__global__ __launch_bounds__(256) void outproj_kernel(const float* __restrict__ ctx,
                                                      const float* __restrict__ Wo,
                                                      const float* __restrict__ bo,
                                                      float* __restrict__ out) {
  __shared__ float sw[32 * 32];
  __shared__ float sb2[32];
  int tid = threadIdx.x;
  for (int i = tid; i < 1024; i += 256) sw[i] = Wo[i];
  if (tid < 32) sb2[tid] = bo[tid];
  __syncthreads();
  size_t row = (size_t)blockIdx.x * 256 + tid;   // grid covers 200704 exactly
  const float* cr = ctx + row * 32;
  v2f xr2[16];
#pragma unroll
  for (int e = 0; e < 8; ++e) {
    float4 f = ((const float4*)cr)[e];
    v2f lo = {f.x, f.y}, hi = {f.z, f.w};
    xr2[2 * e] = lo; xr2[2 * e + 1] = hi;
  }
  float* op = out + row * 32;
#pragma unroll
  for (int d4 = 0; d4 < 8; ++d4) {
    float4 o;
    float* oo = (float*)&o;
#pragma unroll
    for (int q = 0; q < 4; ++q) {
      int d = d4 * 4 + q;
      oo[q] = dot32v(xr2, sw + d * 32, sb2[d]);
    }
    ((float4*)op)[d4] = o;
  }
}

extern "C" void kernel_launch(void* const* d_in, const int* in_sizes, int n_in,
                              void* d_out, int out_size, void* d_ws, size_t ws_size,
                              hipStream_t stream) {
  const float* x  = (const float*)d_in[0];
  const float* cw = (const float*)d_in[1];
  const float* ce = (const float*)d_in[2];
  const float* wq = (const float*)d_in[3];
  const float* bq = (const float*)d_in[4];
  const float* wo = (const float*)d_in[5];
  const float* bo = (const float*)d_in[6];
  float* out = (float*)d_out;
  float* ws  = (float*)d_ws;

  // ws layout (floats): ctx [NB*HW*DD] | pos [196*32] | wtg [84*152]
  float* ctx = ws;
  float* pos = ws + (size_t)NB * HW * DD;
  float* wtg = pos + HW * DD;

  prep2_kernel<<<(HW * DD + 84 * 152 + 255) / 256, 256, 0, stream>>>(cw, wtg, pos);
  fused_kernel<<<NB, 1024, 0, stream>>>(x, wtg, ce, pos, out);   // seq -> d_out
  attn_kernel<<<NB, 832, 0, stream>>>(out, wq, bq, ctx);         // ctx -> ws
  outproj_kernel<<<(NB * HW * DD) / (256 * 32), 256, 0, stream>>>(ctx, wo, bo, out);
}

// Round 8
// 401.248 us; speedup vs baseline: 1.0082x; 1.0082x over previous
//
#include <hip/hip_runtime.h>
#include <math.h>

#define NC1 150
#define HW 196          // 14*14
#define NB 1024
#define DD 32
#define NHD 4
#define HDIM 8
#define KG 2352         // ceil(0.08 * 150*14*14)
#define KCH 10
#define CAP 48          // per-location survivor capacity (avg ~15, +7sd safe)
#define CVS 49          // candV row stride (odd -> conflict-free merge reads)
#define CES 36          // staged CE row stride (16B-aligned rows for float4)
#define KVS 20          // kv row stride in floats (80B rows: b128 writes tile 32 banks)

typedef float v2f __attribute__((ext_vector_type(2)));

// packed-fp32 32-dot: 16 v_pk_fma_f32 + pair-reduce (outproj only)
__device__ __forceinline__ float dot32v(const v2f* __restrict__ xr2,
                                        const float* __restrict__ wr, float bias) {
  const float4* w4 = (const float4*)wr;
  v2f s0 = {bias, 0.f};
  v2f s1 = {0.f, 0.f};
#pragma unroll
  for (int e = 0; e < 8; ++e) {
    float4 w = w4[e];
    v2f wlo = {w.x, w.y}, whi = {w.z, w.w};
    s0 = __builtin_elementwise_fma(xr2[2 * e], wlo, s0);
    s1 = __builtin_elementwise_fma(xr2[2 * e + 1], whi, s1);
  }
  v2f s = s0 + s1;
  return s.x + s.y;
}

// union LDS (float slots):
//  conv phase : XT[42][196] @0 (8232) | WT[42][152] @8232 (6384)  -> 14616
//  tail phase : candV @0 (196*49=9604) | candC u8 @9604 (196*48 B = 2352 slots)
//               | cnt u32 @11956 (196) | CEs @12152 (150*36=5400) -> 17552
#define UNI_F 17552
#define XT_OFF 0
#define WT_OFF 8232
#define CV_OFF 0
#define CC_OFF 9604
#define CNT_OFF 11956
#define CE_OFF 12152

// ---------------- K0 (merged): pos2d [196,32] + conv-weight transpose ----------------
__global__ void prep2_kernel(const float* __restrict__ cw, float* __restrict__ wtg,
                             float* __restrict__ pos) {
  int i = blockIdx.x * 256 + threadIdx.x;
  if (i < HW * DD) {
    int s = i >> 5, d = i & 31;
    int h = s / 14, w = s % 14;
    int p = (d < 16) ? h : w;
    int dd = (d < 16) ? d : d - 16;
    int j = dd >> 1;
    float dv = expf(-(logf(10000.0f) / 16.0f) * (float)(2 * j));
    float ang = (float)p * dv;
    pos[i] = (dd & 1) ? cosf(ang) : sinf(ang);
    return;
  }
  int j = i - HW * DD;
  if (j < 84 * 152) {
    int k = j / 152, c = j - k * 152;
    wtg[j] = (k < 81 && c < NC1) ? cw[c * 81 + k] : 0.f;
  }
}

// ---------------- K1 (fused, R10): conv GEMM -> register radix kth ->
//                  survivor compaction -> per-loc merge top10 + embed + PE ----------
__global__ __launch_bounds__(1024, 8) void fused_kernel(const float* __restrict__ x,
                                                        const float* __restrict__ wtg,
                                                        const float* __restrict__ CE,
                                                        const float* __restrict__ pos,
                                                        float* __restrict__ seqo) {
  __shared__ alignas(16) float uni[UNI_F];   // 70208 B
  __shared__ alignas(16) float xs[784];      // 3136 B
  __shared__ unsigned hist[2048];            // 8192 B
  __shared__ unsigned wsum[4];
  __shared__ unsigned s_prefix, s_krem, s_max;   // total ~79.7 KB -> 2 blocks/CU

  int b = blockIdx.x, tid = threadIdx.x;
  int lane = tid & 63, wid = tid >> 6;

  if (tid < 196) ((float4*)xs)[tid] = ((const float4*)(x + (size_t)b * 784))[tid];
  if (tid == 0) { s_prefix = 0u; s_krem = KG; s_max = 0u; }
  __syncthreads();

  int cg = tid / 49;              // ch-group 0..18 (8 ch each, 152 incl 2 pad)
  int g  = tid - cg * 49;         // loc-group 0..48 (4 locs each, 196 exact)
  bool act = (tid < 931);         // 19*49
  float acc[4][8];
#pragma unroll
  for (int i = 0; i < 4; ++i)
#pragma unroll
    for (int j = 0; j < 8; ++j) acc[i][j] = 0.f;

  float* XT = uni + XT_OFF;       // [42][196]
  float* WT = uni + WT_OFF;       // [42][152]

  for (int kb = 0; kb < 84; kb += 42) {
    // build X^T[kk][s]
    for (int i = tid; i < 42 * 196; i += 1024) {
      int kk = i / 196, s = i - kk * 196;
      int k = kb + kk;
      float v = 0.f;
      if (k < 81) {
        int ki = k / 9, kj = k - ki * 9;
        int h = s / 14, w = s - h * 14;
        int r = 2 * h - 4 + ki, c = 2 * w - 4 + kj;
        if (r >= 0 && r < 28 && c >= 0 && c < 28) v = xs[r * 28 + c];
      }
      XT[i] = v;
    }
    // coalesced float4 copy of pre-transposed weights
    for (int i = tid; i < (42 * 152) / 4; i += 1024)
      ((float4*)WT)[i] = ((const float4*)(wtg + kb * 152))[i];
    __syncthreads();
    if (act) {
      const float* xtp = XT + 4 * g;
      const float* wtp = WT + 8 * cg;
#pragma unroll 7
      for (int kk = 0; kk < 42; ++kk) {
        float4 xv = *(const float4*)(xtp + kk * 196);
        float4 w0 = *(const float4*)(wtp + kk * 152);
        float4 w1 = *(const float4*)(wtp + kk * 152 + 4);
        float xa[4] = {xv.x, xv.y, xv.z, xv.w};
        float wa[8] = {w0.x, w0.y, w0.z, w0.w, w1.x, w1.y, w1.z, w1.w};
#pragma unroll
        for (int i = 0; i < 4; ++i)
#pragma unroll
          for (int j = 0; j < 8; ++j) acc[i][j] += xa[i] * wa[j];
      }
    }
    __syncthreads();              // GEMM reads done before next-phase overwrite
  }

  // ---- ReLU in registers (inactive threads already hold zeros) ----
#pragma unroll
  for (int i = 0; i < 4; ++i)
#pragma unroll
    for (int j = 0; j < 8; ++j) acc[i][j] = fmaxf(acc[i][j], 0.f);

  // ---- kth: 3-pass radix select, histograms fed FROM REGISTERS, zero-skip ----
  for (int pass = 0; pass < 3; ++pass) {
    hist[tid] = 0u; hist[tid + 1024] = 0u;
    __syncthreads();
    int shift = (pass == 0) ? 21 : (pass == 1 ? 10 : 0);
    int bits = (pass == 2) ? 10 : 11;
    unsigned mask = (1u << bits) - 1u;
    unsigned pfx = s_prefix;        // snapshot after barrier
    unsigned krem = s_krem;
    int hishift = shift + bits;
    if (pass == 0) {
      unsigned mymax = 0u;
#pragma unroll
      for (int i = 0; i < 4; ++i)
#pragma unroll
        for (int j = 0; j < 8; ++j) {
          unsigned u = __float_as_uint(acc[i][j]);
          mymax = max(mymax, u);
          if (u) atomicAdd(&hist[u >> 21], 1u);
        }
#pragma unroll
      for (int st = 32; st >= 1; st >>= 1)
        mymax = max(mymax, (unsigned)__shfl_xor((int)mymax, st));
      if (lane == 0) atomicMax(&s_max, mymax);
    } else {
#pragma unroll
      for (int i = 0; i < 4; ++i)
#pragma unroll
        for (int j = 0; j < 8; ++j) {
          unsigned u = __float_as_uint(acc[i][j]);
          if (u && (u >> hishift) == pfx) atomicAdd(&hist[(u >> shift) & mask], 1u);
        }
    }
    __syncthreads();
    int segsz = (1 << bits) >> 8;   // 8 or 4
    unsigned segv = 0u, sufv = 0u;
    if (tid < 256) {
      for (int j = 0; j < segsz; ++j) segv += hist[tid * segsz + j];
      sufv = segv;
#pragma unroll
      for (int st = 1; st < 64; st <<= 1) {
        unsigned o = (unsigned)__shfl_down((int)sufv, st);
        if (lane + st < 64) sufv += o;
      }
      if (lane == 0) wsum[wid] = sufv;
    }
    __syncthreads();
    if (tid < 256) {
      unsigned tail = 0u;
      for (int ww = wid + 1; ww < 4; ++ww) tail += wsum[ww];
      sufv += tail;                    // count in segments >= tid
      unsigned above = sufv - segv;
      if (above < krem && sufv >= krem) {   // unique winner
        unsigned cum = above;
        int dsel = tid * segsz;
        for (int d2 = segsz - 1; d2 >= 0; --d2) {
          int dd = tid * segsz + d2;
          if (cum + hist[dd] >= krem) { dsel = dd; break; }
          cum += hist[dd];
        }
        s_prefix = (pfx << bits) | (unsigned)dsel;
        s_krem = krem - cum;
      }
    }
    __syncthreads();
  }

  // ---- survivor compaction: per-location candidate lists in union LDS ----
  float* candV = uni + CV_OFF;
  unsigned char* candC = (unsigned char*)(uni + CC_OFF);
  unsigned* cnt = (unsigned*)(uni + CNT_OFF);
  if (tid < 196) cnt[tid] = 0u;
  __syncthreads();
  float T = __uint_as_float(s_prefix);
  if (act) {
#pragma unroll
    for (int i = 0; i < 4; ++i) {
      int loc = 4 * g + i;
#pragma unroll
      for (int j = 0; j < 8; ++j) {
        float v = acc[i][j];
        if (v >= T && v > 0.f) {      // pad channels (c>=150) are exact zeros
          unsigned slot = atomicAdd(&cnt[loc], 1u);
          if (slot < CAP) {
            candV[loc * CVS + slot] = v;
            candC[loc * CAP + slot] = (unsigned char)(8 * cg + j);
          }
        }
      }
    }
  }
  __syncthreads();

  // ---- merge (tid<196) overlapped with CE staging (tid>=196) ----
  float* CEs = uni + CE_OFF;          // [150][36], float4-aligned rows
  if (tid >= 196) {
    for (int i = tid - 196; i < NC1 * 32; i += 1024 - 196) {
      int c = i >> 5, e = i & 31;
      CEs[c * CES + e] = CE[i];
    }
  }
  float tv[KCH]; int tc[KCH];
  if (tid < 196) {
    int loc = tid;
    unsigned n = cnt[loc]; if (n > CAP) n = CAP;
#pragma unroll
    for (int k = 0; k < KCH; ++k) { tv[k] = 0.f; tc[k] = 0; }
    for (unsigned jj = 0; jj < n; ++jj) {
      float v = candV[loc * CVS + jj];
      int c = candC[loc * CAP + jj];
      // exact reference semantics: order by value desc, tie -> lower channel
      if (v > tv[KCH - 1] || (v == tv[KCH - 1] && c < tc[KCH - 1])) {
        float iv = v; int ic = c;
#pragma unroll
        for (int j = 0; j < KCH; ++j) {
          bool gt = (iv > tv[j]) || (iv == tv[j] && ic < tc[j]);
          float nv = gt ? iv : tv[j]; int nc = gt ? ic : tc[j];
          float ov = gt ? tv[j] : iv; int oc = gt ? tc[j] : ic;
          tv[j] = nv; tc[j] = nc; iv = ov; ic = oc;
        }
      }
    }
  }
  __syncthreads();                    // CEs staged, merge done

  // ---- embed + PE + write seq ----
  if (tid < 196) {
    float gm = __uint_as_float(s_max);
    float gi = (gm == 0.0f) ? 0.0f : 1.0f / gm;
    float acc2[32];
#pragma unroll
    for (int e = 0; e < 32; ++e) acc2[e] = 0.f;
#pragma unroll
    for (int k = 0; k < KCH; ++k) {   // unused slots have tv=0 -> no-op
      float v = tv[k];
      const float4* cr = (const float4*)(CEs + tc[k] * CES);
#pragma unroll
      for (int e4 = 0; e4 < 8; ++e4) {
        float4 cv = cr[e4];
        acc2[e4 * 4 + 0] += v * cv.x;
        acc2[e4 * 4 + 1] += v * cv.y;
        acc2[e4 * 4 + 2] += v * cv.z;
        acc2[e4 * 4 + 3] += v * cv.w;
      }
    }
    float* op = seqo + ((size_t)b * HW + tid) * DD;
    const float* pr = pos + tid * DD;
#pragma unroll
    for (int e4 = 0; e4 < 8; ++e4) {
      float4 pv = ((const float4*)pr)[e4];
      float4 o;
      o.x = acc2[e4 * 4 + 0] * gi + pv.x;
      o.y = acc2[e4 * 4 + 1] * gi + pv.y;
      o.z = acc2[e4 * 4 + 2] * gi + pv.z;
      o.w = acc2[e4 * 4 + 3] * gi + pv.w;
      ((float4*)op)[e4] = o;
    }
  }
}

// ---------------- K4 (R17): MHA, R12 scalar body + explicit sw-pipelined t-loop ----
// R15/R16 retro: VALU- (pk, -40% issues) and LDS-instr- (2-row tiling, -50%)
// reductions both failed to beat R12's 160us; R16 regressed (+22us with half the
// waves). Elimination leaves per-wave DEP-CHAIN LATENCY (ds_read->dot->exp) with
// too few rows in flight (compiler chose VGPR 40-52 ~= 1 row buffered). R17:
// revert to R12 scalar body (session-best) + EXPLICIT register double-buffer:
// next row's 4 ds_read_b128 issue before current row's compute, consumed after
// -> >=1 row always in flight, unroll 2 rotates buffers. exp2 prefolded.
__global__ __launch_bounds__(832, 3) void attn_kernel(const float* __restrict__ seq,
                                                      const float* __restrict__ Wqkv,
                                                      const float* __restrict__ bqkv,
                                                      float* __restrict__ ctxo) {
  __shared__ alignas(16) float kvs[NHD * HW * KVS];  // 62720 B
  __shared__ alignas(16) float swq[96 * DD];         // 12288 B
  __shared__ float sbq[96];
  __shared__ unsigned s_kk[NHD];                     // total ~75.4 KB

  int b = blockIdx.x, tid = threadIdx.x;
  int h = tid / HW;               // 0..3 (tid<784)
  int s = tid - h * HW;
  bool act = (tid < NHD * HW);

  // hoist global seq row load: HBM latency hides under LDS weight staging
  float xr[32];
  if (act) {
    const float* row = seq + ((size_t)b * HW + s) * DD;
#pragma unroll
    for (int e = 0; e < 8; ++e) {
      float4 f = ((const float4*)row)[e];
      xr[e * 4 + 0] = f.x; xr[e * 4 + 1] = f.y; xr[e * 4 + 2] = f.z; xr[e * 4 + 3] = f.w;
    }
  }
  for (int i = tid; i < (96 * DD) / 4; i += 832)
    ((float4*)swq)[i] = ((const float4*)Wqkv)[i];
  if (tid < 96) sbq[tid] = bqkv[tid];
  if (tid < NHD) s_kk[tid] = 0u;
  __syncthreads();

  float q[8]; float qq = 0.f;
  if (act) {
    float* kvrow = kvs + (h * HW + s) * KVS;
    // ---- k rows (8 dots), track k.k ----
    {
      float ka[8]; float kk = 0.f;
#pragma unroll
      for (int d = 0; d < 8; ++d) {
        const float* wr = swq + (32 + h * HDIM + d) * DD;
        float acc = sbq[32 + h * HDIM + d];
#pragma unroll
        for (int e = 0; e < DD; e += 4) {
          float4 wv = *(const float4*)(wr + e);
          acc += xr[e + 0] * wv.x + xr[e + 1] * wv.y + xr[e + 2] * wv.z + xr[e + 3] * wv.w;
        }
        ka[d] = acc; kk += acc * acc;
      }
      float4 k0 = {ka[0], ka[1], ka[2], ka[3]}, k1 = {ka[4], ka[5], ka[6], ka[7]};
      ((float4*)kvrow)[0] = k0; ((float4*)kvrow)[1] = k1;
      atomicMax(&s_kk[h], __float_as_uint(kk));
    }
    // ---- v rows ----
    {
      float va[8];
#pragma unroll
      for (int d = 0; d < 8; ++d) {
        const float* wr = swq + (64 + h * HDIM + d) * DD;
        float acc = sbq[64 + h * HDIM + d];
#pragma unroll
        for (int e = 0; e < DD; e += 4) {
          float4 wv = *(const float4*)(wr + e);
          acc += xr[e + 0] * wv.x + xr[e + 1] * wv.y + xr[e + 2] * wv.z + xr[e + 3] * wv.w;
        }
        va[d] = acc;
      }
      float4 v0 = {va[0], va[1], va[2], va[3]}, v1 = {va[4], va[5], va[6], va[7]};
      ((float4*)kvrow)[2] = v0; ((float4*)kvrow)[3] = v1;
    }
    // ---- q row (registers only) ----
#pragma unroll
    for (int d = 0; d < 8; ++d) {
      const float* wr = swq + (h * HDIM + d) * DD;
      float acc = sbq[h * HDIM + d];
#pragma unroll
      for (int e = 0; e < DD; e += 4) {
        float4 wv = *(const float4*)(wr + e);
        acc += xr[e + 0] * wv.x + xr[e + 1] * wv.y + xr[e + 2] * wv.z + xr[e + 3] * wv.w;
      }
      q[d] = acc; qq += acc * acc;
    }
  }
  __syncthreads();
  if (!act) return;

  // ---- single-pass softmax (Cauchy-Schwarz shift), explicit 2-stage pipeline ----
  const float scaleL = 0.3535533905932738f * 1.4426950408889634f;  // scale*log2e
  float kkmax = __uint_as_float(s_kk[h]);
  float negML = -sqrtf(qq * kkmax) * scaleL;
  float l = 0.f;
  float c0 = 0.f, c1 = 0.f, c2 = 0.f, c3 = 0.f, c4 = 0.f, c5 = 0.f, c6 = 0.f, c7 = 0.f;
  const float4* kp = (const float4*)(kvs + (h * HW) * KVS);
  float4 k0 = kp[0], k1 = kp[1], v0 = kp[2], v1 = kp[3];   // prologue: row 0
#pragma unroll 2
  for (int t = 0; t < HW - 1; ++t) {
    const float4* np = kp + 5;                             // 80B row
    float4 nk0 = np[0], nk1 = np[1], nv0 = np[2], nv1 = np[3];  // prefetch t+1
    float sc = q[0] * k0.x;
    sc = fmaf(q[1], k0.y, sc); sc = fmaf(q[2], k0.z, sc); sc = fmaf(q[3], k0.w, sc);
    sc = fmaf(q[4], k1.x, sc); sc = fmaf(q[5], k1.y, sc); sc = fmaf(q[6], k1.z, sc);
    sc = fmaf(q[7], k1.w, sc);
    float p = exp2f(fmaf(sc, scaleL, negML));   // bare v_exp_f32
    l += p;
    c0 = fmaf(p, v0.x, c0); c1 = fmaf(p, v0.y, c1); c2 = fmaf(p, v0.z, c2);
    c3 = fmaf(p, v0.w, c3); c4 = fmaf(p, v1.x, c4); c5 = fmaf(p, v1.y, c5);
    c6 = fmaf(p, v1.z, c6); c7 = fmaf(p, v1.w, c7);
    k0 = nk0; k1 = nk1; v0 = nv0; v1 = nv1;
    kp = np;
  }
  {  // epilogue: row 195
    float sc = q[0] * k0.x;
    sc = fmaf(q[1], k0.y, sc); sc = fmaf(q[2], k0.z, sc); sc = fmaf(q[3], k0.w, sc);
    sc = fmaf(q[4], k1.x, sc); sc = fmaf(q[5], k1.y, sc); sc = fmaf(q[6], k1.z, sc);
    sc = fmaf(q[7], k1.w, sc);
    float p = exp2f(fmaf(sc, scaleL, negML));
    l += p;
    c0 = fmaf(p, v0.x, c0); c1 = fmaf(p, v0.y, c1); c2 = fmaf(p, v0.z, c2);
    c3 = fmaf(p, v0.w, c3); c4 = fmaf(p, v1.x, c4); c5 = fmaf(p, v1.y, c5);
    c6 = fmaf(p, v1.z, c6); c7 = fmaf(p, v1.w, c7);
  }
  float inv = 1.0f / l;
  float* op = ctxo + ((size_t)b * HW + s) * DD + h * HDIM;
  float4 o0, o1;
  o0.x = c0 * inv; o0.y = c1 * inv; o0.z = c2 * inv; o0.w = c3 * inv;
  o1.x = c4 * inv; o1.y = c5 * inv; o1.z = c6 * inv; o1.w = c7 * inv;
  ((float4*)op)[0] = o0; ((float4*)op)[1] = o1;
}

// ---------------- K5: out projection, 1 thread per row (packed fp32) ----------------
__global__ __launch_bounds__(256) void outproj_kernel(const float* __restrict__ ctx,
                                                      const float* __restrict__ Wo,
                                                      const float* __restrict__ bo,
                                                      float* __restrict__ out) {
  __shared__ float sw[32 * 32];
  __shared__ float sb2[32];
  int tid = threadIdx.x;
  for (int i = tid; i < 1024; i += 256) sw[i] = Wo[i];
  if (tid < 32) sb2[tid] = bo[tid];
  __syncthreads();
  size_t row = (size_t)blockIdx.x * 256 + tid;   // grid covers 200704 exactly
  const float* cr = ctx + row * 32;
  v2f xr2[16];
#pragma unroll
  for (int e = 0; e < 8; ++e) {
    float4 f = ((const float4*)cr)[e];
    v2f lo = {f.x, f.y}, hi = {f.z, f.w};
    xr2[2 * e] = lo; xr2[2 * e + 1] = hi;
  }
  float* op = out + row * 32;
#pragma unroll
  for (int d4 = 0; d4 < 8; ++d4) {
    float4 o;
    float* oo = (float*)&o;
#pragma unroll
    for (int q = 0; q < 4; ++q) {
      int d = d4 * 4 + q;
      oo[q] = dot32v(xr2, sw + d * 32, sb2[d]);
    }
    ((float4*)op)[d4] = o;
  }
}

extern "C" void kernel_launch(void* const* d_in, const int* in_sizes, int n_in,
                              void* d_out, int out_size, void* d_ws, size_t ws_size,
                              hipStream_t stream) {
  const float* x  = (const float*)d_in[0];
  const float* cw = (const float*)d_in[1];
  const float* ce = (const float*)d_in[2];
  const float* wq = (const float*)d_in[3];
  const float* bq = (const float*)d_in[4];
  const float* wo = (const float*)d_in[5];
  const float* bo = (const float*)d_in[6];
  float* out = (float*)d_out;
  float* ws  = (float*)d_ws;

  // ws layout (floats): ctx [NB*HW*DD] | pos [196*32] | wtg [84*152]
  float* ctx = ws;
  float* pos = ws + (size_t)NB * HW * DD;
  float* wtg = pos + HW * DD;

  prep2_kernel<<<(HW * DD + 84 * 152 + 255) / 256, 256, 0, stream>>>(cw, wtg, pos);
  fused_kernel<<<NB, 1024, 0, stream>>>(x, wtg, ce, pos, out);   // seq -> d_out
  attn_kernel<<<NB, 832, 0, stream>>>(out, wq, bq, ctx);         // ctx -> ws
  outproj_kernel<<<(NB * HW * DD) / (256 * 32), 256, 0, stream>>>(ctx, wo, bo, out);
}